// Round 2
// baseline (7920.046 us; speedup 1.0000x reference)
//
#include <hip/hip_runtime.h>
#include <math.h>

namespace {

constexpr int S = 128;   // seq
constexpr int B = 128;   // batch
constexpr int E = 256;   // embed
constexpr int H = 256;   // hidden

__device__ __forceinline__ float sigmoidf(float x) { return 1.0f / (1.0f + expf(-x)); }

// ---------------- init: copy h0/c0 for the 6 recurrences ----------------
__global__ void init_state(const float* hQ, const float* cQ,
                           const float* hC, const float* cC,
                           const float* hC2, const float* cC2,
                           float* h0, float* c0) {
  int i = blockIdx.x * 256 + threadIdx.x;
  if (i >= 6 * B * H) return;
  int z = i / (B * H);
  int rem = i - z * (B * H);
  int input = z >> 1, dir = z & 1;
  const float* hs = input == 0 ? hQ : (input == 1 ? hC : hC2);
  const float* cs = input == 0 ? cQ : (input == 1 ? cC : cC2);
  h0[i] = hs[dir * B * H + rem];
  c0[i] = cs[dir * B * H + rem];
}

// ================== FAST PATH ==================

// ---------------- input projection: gi[z][t][b][1024] = emb[tok]@Wih^T + bih + bhh ----
// grid (8 colblk, 128 t, 6 z), block 256. Tile 128x128, 8x8/thread, K=256 in chunks of 32.
__global__ __launch_bounds__(256) void lstm_proj(
    const int* __restrict__ idxQ, const int* __restrict__ idxC, const int* __restrict__ idxC2,
    const float* __restrict__ emb,
    const float* __restrict__ Wih_f, const float* __restrict__ bih_f, const float* __restrict__ bhh_f,
    const float* __restrict__ Wih_b, const float* __restrict__ bih_b, const float* __restrict__ bhh_b,
    float* __restrict__ gi)
{
  const int z = blockIdx.z, input = z >> 1, dir = z & 1;
  const int t = blockIdx.y;
  const int n0 = blockIdx.x * 128;
  const int* idx = input == 0 ? idxQ : (input == 1 ? idxC : idxC2);
  const float* W  = dir ? Wih_b : Wih_f;
  const float* b1 = dir ? bih_b : bih_f;
  const float* b2 = dir ? bhh_b : bhh_f;

  __shared__ float Al[128][36];  // [row=b][k] pitch 36: row base 144B (16B mult)
  __shared__ float Bl[128][36];  // [col][k]
  __shared__ int tok[128];
  const int tid = threadIdx.x;
  if (tid < 128) tok[tid] = idx[t * B + tid];
  const int tx = tid & 15, ty = tid >> 4;
  float acc[8][8] = {};

  for (int kb = 0; kb < E; kb += 32) {
    __syncthreads();
#pragma unroll
    for (int i = 0; i < 16; ++i) {
      int e = i * 256 + tid;
      int r = e >> 5, kk = e & 31;
      Al[r][kk] = emb[(long)tok[r] * E + kb + kk];
      Bl[r][kk] = W[(long)(n0 + r) * E + kb + kk];
    }
    __syncthreads();
#pragma unroll
    for (int k4 = 0; k4 < 8; ++k4) {
      float4 a[8], b[8];
#pragma unroll
      for (int i = 0; i < 8; ++i) a[i] = *(const float4*)&Al[ty + 16 * i][k4 * 4];
#pragma unroll
      for (int j = 0; j < 8; ++j) b[j] = *(const float4*)&Bl[tx + 16 * j][k4 * 4];
#pragma unroll
      for (int i = 0; i < 8; ++i)
#pragma unroll
        for (int j = 0; j < 8; ++j)
          acc[i][j] += a[i].x * b[j].x + a[i].y * b[j].y + a[i].z * b[j].z + a[i].w * b[j].w;
    }
  }
  float* gp = gi + (long)(z * S + t) * B * 1024;
#pragma unroll
  for (int i = 0; i < 8; ++i) {
    int r = ty + 16 * i;
#pragma unroll
    for (int j = 0; j < 8; ++j) {
      int c = n0 + tx + 16 * j;
      gp[(long)r * 1024 + c] = acc[i][j] + b1[c] + b2[c];
    }
  }
}

// ---------------- recurrent step: g = gi[t] + h@Whh^T, gates, c/h update ----------------
// grid (16 unitblk, 24 = 6z x 4 rowblk), block 128. Tile 32 rows x 64 gate-cols, K=256.
__global__ __launch_bounds__(128) void lstm_step2(
    const float* __restrict__ Whh_f, const float* __restrict__ Whh_b,
    const float* __restrict__ gi, const float* __restrict__ hread,
    float* __restrict__ hwrite, float* __restrict__ cstate,
    float* __restrict__ out3, int t)
{
  const int zy = blockIdx.y;
  const int z = zy >> 2;
  const int b0 = (zy & 3) * 32;
  const int input = z >> 1, dir = z & 1;
  const int u0 = blockIdx.x * 16;
  const int t_eff = dir ? (S - 1 - t) : t;
  const float* Whh = dir ? Whh_b : Whh_f;

  __shared__ float Al[32][68];
  __shared__ float Wl[64][68];
  const int tid = threadIdx.x;
  const int uu = tid & 15, rg = tid >> 4;   // rg 0..7 -> rows rg*4..+3
  const int u = u0 + uu;

  float acc[4][4];  // [ri][gate]
  {
    const float* gp = gi + ((long)(z * S + t_eff) * B + b0) * 1024;
#pragma unroll
    for (int ri = 0; ri < 4; ++ri)
#pragma unroll
      for (int g = 0; g < 4; ++g)
        acc[ri][g] = gp[(long)(rg * 4 + ri) * 1024 + g * 256 + u];
  }

  const float* hs = hread + ((long)z * B + b0) * H;
  for (int kc = 0; kc < 4; ++kc) {
    const int kb = kc * 64;
    __syncthreads();
#pragma unroll
    for (int i = 0; i < 4; ++i) {       // A: 32 rows x 16 f4
      int e = i * 128 + tid;
      int r = e >> 4, k4 = e & 15;
      *(float4*)&Al[r][k4 * 4] = *(const float4*)&hs[r * H + kb + k4 * 4];
    }
#pragma unroll
    for (int i = 0; i < 8; ++i) {       // W: 64 cols x 16 f4
      int e = i * 128 + tid;
      int c = e >> 4, k4 = e & 15;
      int gcol = (c >> 4) * 256 + u0 + (c & 15);
      *(float4*)&Wl[c][k4 * 4] = *(const float4*)&Whh[(long)gcol * H + kb + k4 * 4];
    }
    __syncthreads();
#pragma unroll
    for (int k4 = 0; k4 < 64; k4 += 4) {
      float4 a[4], w[4];
#pragma unroll
      for (int ri = 0; ri < 4; ++ri) a[ri] = *(const float4*)&Al[rg * 4 + ri][k4];
#pragma unroll
      for (int g = 0; g < 4; ++g) w[g] = *(const float4*)&Wl[g * 16 + uu][k4];
#pragma unroll
      for (int ri = 0; ri < 4; ++ri)
#pragma unroll
        for (int g = 0; g < 4; ++g)
          acc[ri][g] += a[ri].x * w[g].x + a[ri].y * w[g].y
                      + a[ri].z * w[g].z + a[ri].w * w[g].w;
    }
  }

  float* cs = cstate + (long)z * B * H;
  float* hw = hwrite + (long)z * B * H;
  float* op = out3 + (long)input * B * S * 2 * H;
#pragma unroll
  for (int ri = 0; ri < 4; ++ri) {
    int b = b0 + rg * 4 + ri;
    float ig = sigmoidf(acc[ri][0]);
    float fg = sigmoidf(acc[ri][1]);
    float gg = tanhf(acc[ri][2]);
    float og = sigmoidf(acc[ri][3]);
    float cn = fg * cs[b * H + u] + ig * gg;
    float hn = og * tanhf(cn);
    cs[b * H + u] = cn;
    hw[b * H + u] = hn;
    op[((long)b * S + t_eff) * (2 * H) + dir * H + u] = hn;
  }
}

// ---------------- 128x128-tile fp32 GEMM, 8x8/thread ----------------
// NT: C = act(A@B^T [+bias]);  NN: C = A@B.  K%32==0, M%128==0, N%128==0.
// grid (N/128, M/128, batch), block 256.
template <bool NT, bool TANH, bool BIAS>
__global__ __launch_bounds__(256) void gemm8(
    const float* __restrict__ A, const float* __restrict__ Bm,
    const float* __restrict__ bias, float* __restrict__ C,
    int lda, int ldb, int ldc, int K, long sA, long sB, long sC)
{
  A += blockIdx.z * sA; Bm += blockIdx.z * sB; C += blockIdx.z * sC;
  const int n0 = blockIdx.x * 128, m0 = blockIdx.y * 128;
  __shared__ float Al[128][36];
  __shared__ float Bl[128][36];
  const int tid = threadIdx.x;
  const int tx = tid & 15, ty = tid >> 4;
  float acc[8][8] = {};
  for (int kb = 0; kb < K; kb += 32) {
    __syncthreads();
#pragma unroll
    for (int i = 0; i < 16; ++i) {
      int e = i * 256 + tid;
      int r = e >> 5, kk = e & 31;
      Al[r][kk] = A[(long)(m0 + r) * lda + kb + kk];
    }
    if (NT) {
#pragma unroll
      for (int i = 0; i < 16; ++i) {
        int e = i * 256 + tid;
        int c = e >> 5, kk = e & 31;
        Bl[c][kk] = Bm[(long)(n0 + c) * ldb + kb + kk];
      }
    } else {
#pragma unroll
      for (int i = 0; i < 16; ++i) {
        int e = i * 256 + tid;
        int c = e & 127, kk = e >> 7;
        Bl[c][kk] = Bm[(long)(kb + kk) * ldb + n0 + c];
      }
    }
    __syncthreads();
#pragma unroll
    for (int k4 = 0; k4 < 8; ++k4) {
      float4 a[8], b[8];
#pragma unroll
      for (int i = 0; i < 8; ++i) a[i] = *(const float4*)&Al[ty + 16 * i][k4 * 4];
#pragma unroll
      for (int j = 0; j < 8; ++j) b[j] = *(const float4*)&Bl[tx + 16 * j][k4 * 4];
#pragma unroll
      for (int i = 0; i < 8; ++i)
#pragma unroll
        for (int j = 0; j < 8; ++j)
          acc[i][j] += a[i].x * b[j].x + a[i].y * b[j].y + a[i].z * b[j].z + a[i].w * b[j].w;
    }
  }
#pragma unroll
  for (int i = 0; i < 8; ++i) {
    int m = m0 + ty + 16 * i;
#pragma unroll
    for (int j = 0; j < 8; ++j) {
      int n = n0 + tx + 16 * j;
      float v = acc[i][j];
      if (BIAS) v += bias[n];
      if (TANH) v = tanhf(v);
      C[(long)m * ldc + n] = v;
    }
  }
}

// ================== FALLBACK PATH (round-1, verified) ==================

__global__ __launch_bounds__(256) void lstm_step(
    const int* __restrict__ idxQ, const int* __restrict__ idxC, const int* __restrict__ idxC2,
    const float* __restrict__ emb,
    const float* __restrict__ Wih_f, const float* __restrict__ Whh_f,
    const float* __restrict__ bih_f, const float* __restrict__ bhh_f,
    const float* __restrict__ Wih_b, const float* __restrict__ Whh_b,
    const float* __restrict__ bih_b, const float* __restrict__ bhh_b,
    const float* __restrict__ hread, float* __restrict__ hwrite,
    float* __restrict__ cstate, float* __restrict__ out3, int t)
{
  const int z = blockIdx.z;
  const int input = z >> 1, dir = z & 1;
  const int u0 = blockIdx.x * 16;
  const int b0 = blockIdx.y * 64;
  const int t_eff = dir ? (S - 1 - t) : t;
  const int* idx = input == 0 ? idxQ : (input == 1 ? idxC : idxC2);
  const float* Wih = dir ? Wih_b : Wih_f;
  const float* Whh = dir ? Whh_b : Whh_f;
  const float* bih = dir ? bih_b : bih_f;
  const float* bhh = dir ? bhh_b : bhh_f;

  __shared__ float Al[64][68];
  __shared__ float Wl[64][68];
  __shared__ int tok[64];

  const int tid = threadIdx.x;
  if (tid < 64) tok[tid] = idx[t_eff * B + b0 + tid];

  const int uu = tid & 15;
  const int rg = tid >> 4;
  const int u = u0 + uu;

  float acc[4][4];
#pragma unroll
  for (int ri = 0; ri < 4; ++ri)
#pragma unroll
    for (int g = 0; g < 4; ++g)
      acc[ri][g] = bih[g * 256 + u] + bhh[g * 256 + u];

  for (int kc = 0; kc < 8; ++kc) {
    __syncthreads();
    if (kc < 4) {
      const int kb = kc * 64;
#pragma unroll
      for (int i = 0; i < 16; ++i) {
        int e = i * 256 + tid;
        int kk = e & 63, r = e >> 6;
        Al[r][kk] = emb[(long)tok[r] * E + kb + kk];
      }
    } else {
      const int kb = (kc - 4) * 64;
      const float* hs = hread + ((long)z * B + b0) * H + kb;
#pragma unroll
      for (int i = 0; i < 16; ++i) {
        int e = i * 256 + tid;
        int kk = e & 63, r = e >> 6;
        Al[r][kk] = hs[r * H + kk];
      }
    }
    {
      const float* Wsrc = (kc < 4) ? Wih : Whh;
      const int kb = (kc & 3) * 64;
#pragma unroll
      for (int i = 0; i < 16; ++i) {
        int e = i * 256 + tid;
        int kk = e & 63, c = e >> 6;
        int gcol = (c >> 4) * 256 + u0 + (c & 15);
        Wl[c][kk] = Wsrc[(long)gcol * H + kb + kk];
      }
    }
    __syncthreads();
#pragma unroll
    for (int k4 = 0; k4 < 64; k4 += 4) {
      float4 a[4], w[4];
#pragma unroll
      for (int ri = 0; ri < 4; ++ri) a[ri] = *(const float4*)&Al[rg * 4 + ri][k4];
#pragma unroll
      for (int g = 0; g < 4; ++g) w[g] = *(const float4*)&Wl[g * 16 + uu][k4];
#pragma unroll
      for (int ri = 0; ri < 4; ++ri)
#pragma unroll
        for (int g = 0; g < 4; ++g)
          acc[ri][g] += a[ri].x * w[g].x + a[ri].y * w[g].y
                      + a[ri].z * w[g].z + a[ri].w * w[g].w;
    }
  }

  float* cs = cstate + (long)z * B * H;
  float* hw = hwrite + (long)z * B * H;
  float* op = out3 + (long)input * B * S * 2 * H;
#pragma unroll
  for (int ri = 0; ri < 4; ++ri) {
    int b = b0 + rg * 4 + ri;
    float ig = sigmoidf(acc[ri][0]);
    float fg = sigmoidf(acc[ri][1]);
    float gg = tanhf(acc[ri][2]);
    float og = sigmoidf(acc[ri][3]);
    float cn = fg * cs[b * H + u] + ig * gg;
    float hn = og * tanhf(cn);
    cs[b * H + u] = cn;
    hw[b * H + u] = hn;
    op[((long)b * S + t_eff) * (2 * H) + dir * H + u] = hn;
  }
}

// 64x64-tile NT GEMM (used for Hm in both paths; full fallback use too)
template <bool TANH>
__global__ __launch_bounds__(256) void gemm_nt(
    const float* __restrict__ A, const float* __restrict__ B_,
    const float* __restrict__ bias, float* __restrict__ C,
    int lda, int ldb, int ldc, int K, long sA, long sB, long sC)
{
  A += blockIdx.z * sA; B_ += blockIdx.z * sB; C += blockIdx.z * sC;
  const int n0 = blockIdx.x * 64, m0 = blockIdx.y * 64;
  __shared__ float Al[64][68], Bl[64][68];
  const int tid = threadIdx.x, uu = tid & 15, rg = tid >> 4;
  float acc[4][4] = {};
  for (int kb = 0; kb < K; kb += 64) {
    __syncthreads();
#pragma unroll
    for (int i = 0; i < 16; ++i) {
      int e = i * 256 + tid;
      int kk = e & 63, r = e >> 6;
      Al[r][kk] = A[(long)(m0 + r) * lda + kb + kk];
      Bl[r][kk] = B_[(long)(n0 + r) * ldb + kb + kk];
    }
    __syncthreads();
#pragma unroll
    for (int k4 = 0; k4 < 64; k4 += 4) {
      float4 a[4], w[4];
#pragma unroll
      for (int ri = 0; ri < 4; ++ri) a[ri] = *(const float4*)&Al[rg * 4 + ri][k4];
#pragma unroll
      for (int ci = 0; ci < 4; ++ci) w[ci] = *(const float4*)&Bl[ci * 16 + uu][k4];
#pragma unroll
      for (int ri = 0; ri < 4; ++ri)
#pragma unroll
        for (int ci = 0; ci < 4; ++ci)
          acc[ri][ci] += a[ri].x * w[ci].x + a[ri].y * w[ci].y
                       + a[ri].z * w[ci].z + a[ri].w * w[ci].w;
    }
  }
#pragma unroll
  for (int ri = 0; ri < 4; ++ri) {
    int m = m0 + rg * 4 + ri;
#pragma unroll
    for (int ci = 0; ci < 4; ++ci) {
      int n = n0 + ci * 16 + uu;
      float v = acc[ri][ci];
      if (bias) v += bias[n];
      if (TANH) v = tanhf(v);
      C[(long)m * ldc + n] = v;
    }
  }
}

__global__ __launch_bounds__(256) void gemm_nn(
    const float* __restrict__ A, const float* __restrict__ B_,
    float* __restrict__ C,
    int lda, int ldb, int ldc, int K, long sA, long sB, long sC)
{
  A += blockIdx.z * sA; B_ += blockIdx.z * sB; C += blockIdx.z * sC;
  const int n0 = blockIdx.x * 64, m0 = blockIdx.y * 64;
  __shared__ float Al[64][68];
  __shared__ float Bl[64][68];
  const int tid = threadIdx.x, uu = tid & 15, rg = tid >> 4;
  float acc[4][4] = {};
  for (int kb = 0; kb < K; kb += 64) {
    __syncthreads();
#pragma unroll
    for (int i = 0; i < 16; ++i) {
      int e = i * 256 + tid;
      int kk = e & 63, r = e >> 6;
      Al[r][kk] = A[(long)(m0 + r) * lda + kb + kk];
      Bl[r][kk] = B_[(long)(kb + r) * ldb + n0 + kk];
    }
    __syncthreads();
#pragma unroll
    for (int kk = 0; kk < 64; ++kk) {
      float4 w = *(const float4*)&Bl[kk][uu * 4];
      float a0 = Al[rg * 4 + 0][kk], a1 = Al[rg * 4 + 1][kk];
      float a2 = Al[rg * 4 + 2][kk], a3 = Al[rg * 4 + 3][kk];
      acc[0][0] += a0 * w.x; acc[0][1] += a0 * w.y; acc[0][2] += a0 * w.z; acc[0][3] += a0 * w.w;
      acc[1][0] += a1 * w.x; acc[1][1] += a1 * w.y; acc[1][2] += a1 * w.z; acc[1][3] += a1 * w.w;
      acc[2][0] += a2 * w.x; acc[2][1] += a2 * w.y; acc[2][2] += a2 * w.z; acc[2][3] += a2 * w.w;
      acc[3][0] += a3 * w.x; acc[3][1] += a3 * w.y; acc[3][2] += a3 * w.z; acc[3][3] += a3 * w.w;
    }
  }
#pragma unroll
  for (int ri = 0; ri < 4; ++ri) {
    int m = m0 + rg * 4 + ri;
    float4 v = make_float4(acc[ri][0], acc[ri][1], acc[ri][2], acc[ri][3]);
    *(float4*)&C[(long)m * ldc + n0 + uu * 4] = v;
  }
}

// ---------------- softmaxes ----------------
__global__ void softmax_row(const float* __restrict__ Hm, float* __restrict__ A) {
  const int row = blockIdx.x;
  const float* p = Hm + (long)row * S;
  const int l = threadIdx.x;
  float v0 = p[l], v1 = p[l + 64];
  float m = fmaxf(v0, v1);
#pragma unroll
  for (int o = 32; o > 0; o >>= 1) m = fmaxf(m, __shfl_xor(m, o));
  float e0 = expf(v0 - m), e1 = expf(v1 - m);
  float s = e0 + e1;
#pragma unroll
  for (int o = 32; o > 0; o >>= 1) s += __shfl_xor(s, o);
  float inv = 1.0f / s;
  float* q = A + (long)row * S;
  q[l] = e0 * inv; q[l + 64] = e1 * inv;
}

__global__ void softmax_colT(const float* __restrict__ Hm, float* __restrict__ A) {
  const int b = blockIdx.x >> 7;
  const int col = blockIdx.x & 127;
  const float* p = Hm + (long)b * S * S + col;
  const int l = threadIdx.x;
  float v0 = p[(long)l * S], v1 = p[(long)(l + 64) * S];
  float m = fmaxf(v0, v1);
#pragma unroll
  for (int o = 32; o > 0; o >>= 1) m = fmaxf(m, __shfl_xor(m, o));
  float e0 = expf(v0 - m), e1 = expf(v1 - m);
  float s = e0 + e1;
#pragma unroll
  for (int o = 32; o > 0; o >>= 1) s += __shfl_xor(s, o);
  float inv = 1.0f / s;
  float* q = A + ((long)b * S + col) * S;
  q[l] = e0 * inv; q[l + 64] = e1 * inv;
}

}  // namespace

extern "C" void kernel_launch(void* const* d_in, const int* in_sizes, int n_in,
                              void* d_out, int out_size, void* d_ws, size_t ws_size,
                              hipStream_t stream) {
  const int* idxQ    = (const int*)d_in[1];
  const int* idxC    = (const int*)d_in[2];
  const int* idxC2   = (const int*)d_in[3];
  const float* hQ    = (const float*)d_in[4];
  const float* cQ    = (const float*)d_in[5];
  const float* hC    = (const float*)d_in[6];
  const float* cC    = (const float*)d_in[7];
  const float* hC2   = (const float*)d_in[8];
  const float* cC2   = (const float*)d_in[9];
  const float* emb   = (const float*)d_in[10];
  const float* Wih_f = (const float*)d_in[11];
  const float* Whh_f = (const float*)d_in[12];
  const float* bih_f = (const float*)d_in[13];
  const float* bhh_f = (const float*)d_in[14];
  const float* Wih_b = (const float*)d_in[15];
  const float* Whh_b = (const float*)d_in[16];
  const float* bih_b = (const float*)d_in[17];
  const float* bhh_b = (const float*)d_in[18];
  const float* S1W   = (const float*)d_in[19];
  const float* S1b   = (const float*)d_in[20];
  float* out = (float*)d_out;

  const long OUT1 = (long)B * S * 2 * H;      // 8,388,608 floats
  const long ST   = (long)6 * B * H;          // 196,608 floats
  const long GI   = (long)6 * S * B * 1024;   // 100,663,296 floats

  const size_t need_fast = (size_t)(GI + 3 * OUT1 + 3 * ST) * 4;  // 505,675,776 B

  if (ws_size >= need_fast) {
    // -------- fast path: hoisted input projection --------
    float* ws    = (float*)d_ws;
    float* gi    = ws;
    float* out3  = gi + GI;
    float* hbuf0 = out3 + 3 * OUT1;
    float* hbuf1 = hbuf0 + ST;
    float* cbuf  = hbuf1 + ST;
    // attention scratch aliases gi (gi dead after last lstm_step2)
    float* Ct = ws;
    float* Hm = ws + OUT1;
    float* Ab = Hm + (long)B * S * S;

    init_state<<<(6 * B * H + 255) / 256, 256, 0, stream>>>(hQ, cQ, hC, cC, hC2, cC2, hbuf0, cbuf);

    lstm_proj<<<dim3(8, 128, 6), 256, 0, stream>>>(
        idxQ, idxC, idxC2, emb, Wih_f, bih_f, bhh_f, Wih_b, bih_b, bhh_b, gi);

    for (int t = 0; t < S; ++t) {
      float* hr = (t & 1) ? hbuf1 : hbuf0;
      float* hw = (t & 1) ? hbuf0 : hbuf1;
      lstm_step2<<<dim3(16, 24), 128, 0, stream>>>(
          Whh_f, Whh_b, gi, hr, hw, cbuf, out3, t);
    }

    for (int p = 0; p < 2; ++p) {
      const float* Q  = out3;
      const float* C0 = out3 + (long)(1 + p) * OUT1;
      // Ct = tanh(C0 @ S1W^T + S1b): M=16384, N=512, K=512
      gemm8<true, true, true><<<dim3(4, 128, 1), 256, 0, stream>>>(
          C0, S1W, S1b, Ct, 512, 512, 512, 512, 0, 0, 0);
      // Hm[b] = Q[b] @ Ct[b]^T: per-batch M=N=128, K=512
      gemm_nt<false><<<dim3(2, 2, B), 256, 0, stream>>>(
          Q, Ct, nullptr, Hm, 512, 512, 128, 512,
          (long)S * 512, (long)S * 512, (long)S * S);
      softmax_row<<<B * S, 64, 0, stream>>>(Hm, Ab);
      // MQ[b] = AQ[b] @ Q[b]: M=128, N=512, K=128
      float* MQ = out + (long)(2 * p) * OUT1;
      gemm8<false, false, false><<<dim3(4, 1, B), 256, 0, stream>>>(
          Ab, Q, nullptr, MQ, 128, 512, 512, 128,
          (long)S * S, (long)S * 512, (long)S * 512);
      softmax_colT<<<B * S, 64, 0, stream>>>(Hm, Ab);
      float* MC = out + (long)(2 * p + 1) * OUT1;
      gemm8<false, false, false><<<dim3(4, 1, B), 256, 0, stream>>>(
          Ab, MQ, nullptr, MC, 128, 512, 512, 128,
          (long)S * S, (long)S * 512, (long)S * 512);
    }
    return;
  }

  // -------- fallback path: round-1 verified --------
  float* ws    = (float*)d_ws;
  float* out3  = ws;
  float* hbuf0 = out3 + 3 * OUT1;
  float* hbuf1 = hbuf0 + ST;
  float* cbuf  = hbuf1 + ST;
  float* Ct    = cbuf + ST;
  float* Hm    = Ct + OUT1;
  float* Ab    = Hm + (long)B * S * S;

  init_state<<<(6 * B * H + 255) / 256, 256, 0, stream>>>(hQ, cQ, hC, cC, hC2, cC2, hbuf0, cbuf);

  for (int t = 0; t < S; ++t) {
    float* hr = (t & 1) ? hbuf1 : hbuf0;
    float* hw = (t & 1) ? hbuf0 : hbuf1;
    lstm_step<<<dim3(16, 2, 6), 256, 0, stream>>>(
        idxQ, idxC, idxC2, emb,
        Wih_f, Whh_f, bih_f, bhh_f, Wih_b, Whh_b, bih_b, bhh_b,
        hr, hw, cbuf, out3, t);
  }

  for (int p = 0; p < 2; ++p) {
    const float* Q  = out3;
    const float* C0 = out3 + (long)(1 + p) * OUT1;
    gemm_nt<true><<<dim3(8, 256, 1), 256, 0, stream>>>(
        C0, S1W, S1b, Ct, 512, 512, 512, 512, 0, 0, 0);
    gemm_nt<false><<<dim3(2, 2, B), 256, 0, stream>>>(
        Q, Ct, nullptr, Hm, 512, 512, 128, 512,
        (long)S * 512, (long)S * 512, (long)S * S);
    softmax_row<<<B * S, 64, 0, stream>>>(Hm, Ab);
    float* MQ = out + (long)(2 * p) * OUT1;
    gemm_nn<<<dim3(8, 2, B), 256, 0, stream>>>(
        Ab, Q, MQ, 128, 512, 512, 128,
        (long)S * S, (long)S * 512, (long)S * 512);
    softmax_colT<<<B * S, 64, 0, stream>>>(Hm, Ab);
    float* MC = out + (long)(2 * p + 1) * OUT1;
    gemm_nn<<<dim3(8, 2, B), 256, 0, stream>>>(
        Ab, MQ, MC, 128, 512, 512, 128,
        (long)S * S, (long)S * 512, (long)S * 512);
  }
}